// Round 5
// baseline (8448.167 us; speedup 1.0000x reference)
//
#include <hip/hip_runtime.h>
#include <math.h>

#define TPB  256            // 4 waves of 64
#define SPB  16
#define NBLK 1024           // 16384 / 16

// LDS strides (elements)
#define H_RS  378           // float row stride per sample
#define H_NS  34            // float node stride
#define H1_RS 404           // ushort row stride
#define H1_NS 36            // ushort node stride (72 B, b64-aligned)
#define AG_RS 130           // float stride per sample
#define AG_SL (16*AG_RS)    // slot stride (2 node slots)

// ws offsets (floats)
#define WS_WEFF 0           // [3 int][3 class][128 j][32 f] = 36864
#define WS_W2E  36864       // [3 int][3 class][128 j] = 1152
#define WS_H1C  38016       // [3 int][32 f] const h1 rows
#define WS_PC   38112       // [3] const sigmoid p for nodes 0..2
#define WS_GACC 38120       // [3 int][8 node] sums of p

#define SQRT1EM5 0.0031622776601683794f

__device__ __forceinline__ unsigned f2bf(float x) {
    unsigned u = __float_as_uint(x);
    return (u + 0x7fffu + ((u >> 16) & 1u)) >> 16;
}

// ---------------- main fused kernel ----------------
// lane = s(4b) + ng(1b)*16 + x1(1b)*32 ; wave w in 0..3 -> f-octet f0 = 8w (4x8 = all 32 f)
// chunks (dst-node pairs): C0={3,5} C1={6,7} C2={8,9} (class1)  C3={4,10} (class0,class2)

template<int CONV>
__device__ __forceinline__ void run_conv(
    int s, int ng, int x1, int lane, int f0, int s0g,
    float* sH, unsigned short* sH1, float* sAGG,
    const float* __restrict__ Wpre, const float* __restrict__ bpre,
    const float* __restrict__ WEFF, const float* __restrict__ bpost,   // conv1
    const float* __restrict__ w2,   const float* __restrict__ b2,      // conv2
    const float* __restrict__ h1c,                                     // conv1
    const float* __restrict__ edge_attr, float* gacc, int w)
{
    // tables: [c][it][ng][x1]
    constexpr int ETB[4][2][2][2] = {
        { {{0,2},{3,4}},    {{-1,-1},{-1,-1}} },
        { {{5,6},{7,8}},    {{-1,-1},{-1,-1}} },
        { {{9,10},{11,12}}, {{-1,-1},{-1,-1}} },
        { {{1,-1},{13,15}}, {{-1,-1},{14,16}} },
    };
    constexpr int STB[4][2][2][2] = {      // src node of each edge slot
        { {{0,1},{1,2}},   {{0,0},{0,0}} },
        { {{0,3},{4,5}},   {{0,0},{0,0}} },
        { {{6,7},{2,8}},   {{0,0},{0,0}} },
        { {{0,0},{3,9}},   {{0,0},{6,1}} },
    };
    constexpr int NITER[4] = {1,1,1,2};
    constexpr int NDA[4] = {3,6,8,4}, NDB[4] = {5,7,9,10};

    const float4* eap = (const float4*)(edge_attr + (size_t)(s0g + s) * 68);
    float* pp = sAGG;      // conv2 partial scratch: [4 waves][32 (s,ng)]

#pragma unroll
    for (int c = 0; c < 4; c++) {
        const int nd = ng ? NDB[c] : NDA[c];
        // ---- dst-part + bias -> m_base
        float mb[8];
#pragma unroll
        for (int f = 0; f < 8; f++) mb[f] = bpre[f0 + f];
        if constexpr (CONV == 1) {
            const float2* hp = (const float2*)(sH + s * H_RS + nd * H_NS);
#pragma unroll
            for (int kp = 0; kp < 16; kp++) {
                float2 a = hp[kp];
                const float* w0 = Wpre + (2*kp)*32 + f0;
                const float* w1 = Wpre + (2*kp+1)*32 + f0;
#pragma unroll
                for (int f = 0; f < 8; f++) mb[f] += a.x*w0[f] + a.y*w1[f];
            }
        } else {
            const uint2* hp = (const uint2*)(sH1 + s * H1_RS + nd * H1_NS);
#pragma unroll
            for (int kq = 0; kq < 8; kq++) {
                uint2 a = hp[kq];
                float a0 = __uint_as_float(a.x << 16);
                float a1 = __uint_as_float(a.x & 0xffff0000u);
                float a2 = __uint_as_float(a.y << 16);
                float a3 = __uint_as_float(a.y & 0xffff0000u);
                const float* wr = Wpre + (4*kq)*32 + f0;
#pragma unroll
                for (int f = 0; f < 8; f++)
                    mb[f] += a0*wr[f] + a1*wr[32+f] + a2*wr[64+f] + a3*wr[96+f];
            }
        }
        // ---- edges + streaming stats
        float sm[8], sq[8], mn[8], mx[8];
#pragma unroll
        for (int f = 0; f < 8; f++) { sm[f] = 0.f; sq[f] = 0.f; mn[f] = 1e30f; mx[f] = -1e30f; }
#pragma unroll
        for (int it = 0; it < NITER[c]; it++) {
            const int e  = ng ? (x1 ? ETB[c][it][1][1] : ETB[c][it][1][0])
                              : (x1 ? ETB[c][it][0][1] : ETB[c][it][0][0]);
            const int sn = ng ? (x1 ? STB[c][it][1][1] : STB[c][it][1][0])
                              : (x1 ? STB[c][it][0][1] : STB[c][it][0][0]);
            const bool val = (e >= 0);
            const int  e0  = val ? e : 0;
            float t[8];
            float4 ev = eap[e0];
            {
                const float* wa = Wpre + 64*32 + f0;
#pragma unroll
                for (int f = 0; f < 8; f++)
                    t[f] = ev.x*wa[f] + ev.y*wa[32+f] + ev.z*wa[64+f] + ev.w*wa[96+f];
            }
            if constexpr (CONV == 1) {
                const float2* hp = (const float2*)(sH + s * H_RS + sn * H_NS);
#pragma unroll
                for (int kp = 0; kp < 16; kp++) {
                    float2 a = hp[kp];
                    const float* w0 = Wpre + (32 + 2*kp)*32 + f0;
                    const float* w1 = Wpre + (32 + 2*kp+1)*32 + f0;
#pragma unroll
                    for (int f = 0; f < 8; f++) t[f] += a.x*w0[f] + a.y*w1[f];
                }
            } else {
                const uint2* hp = (const uint2*)(sH1 + s * H1_RS + sn * H1_NS);
#pragma unroll
                for (int kq = 0; kq < 8; kq++) {
                    uint2 a = hp[kq];
                    float a0 = __uint_as_float(a.x << 16);
                    float a1 = __uint_as_float(a.x & 0xffff0000u);
                    float a2 = __uint_as_float(a.y << 16);
                    float a3 = __uint_as_float(a.y & 0xffff0000u);
                    const float* wr = Wpre + (32 + 4*kq)*32 + f0;
#pragma unroll
                    for (int f = 0; f < 8; f++)
                        t[f] += a0*wr[f] + a1*wr[32+f] + a2*wr[64+f] + a3*wr[96+f];
                }
            }
#pragma unroll
            for (int f = 0; f < 8; f++) {
                float m = fmaxf(mb[f] + t[f], 0.f);
                sm[f] += val ? m : 0.f;
                sq[f] += val ? m*m : 0.f;
                mn[f] = fminf(mn[f], val ? m :  1e30f);
                mx[f] = fmaxf(mx[f], val ? m : -1e30f);
            }
        }
        // ---- merge x1 halves
#pragma unroll
        for (int f = 0; f < 8; f++) {
            sm[f] += __shfl_xor(sm[f], 32);
            sq[f] += __shfl_xor(sq[f], 32);
            mn[f] = fminf(mn[f], __shfl_xor(mn[f], 32));
            mx[f] = fmaxf(mx[f], __shfl_xor(mx[f], 32));
        }
        const float inv = ng ? (c == 3 ? 0.25f : 0.5f) : (c == 3 ? 1.0f : 0.5f);

        if constexpr (CONV == 1) {
            // ---- finalize + agg write (x1 == 0 lanes)
            if (x1 == 0) {
                float* ar = sAGG + ng * AG_SL + s * AG_RS;
#pragma unroll
                for (int p = 0; p < 4; p++) {
                    float me0 = sm[2*p] * inv,  me1 = sm[2*p+1] * inv;
                    float q0  = sq[2*p] * inv,  q1  = sq[2*p+1] * inv;
                    float sd0 = sqrtf(fmaxf(q0 - me0*me0, 0.f) + 1e-5f);
                    float sd1 = sqrtf(fmaxf(q1 - me1*me1, 0.f) + 1e-5f);
                    *(float2*)(ar +       f0 + 2*p) = make_float2(me0, me1);
                    *(float2*)(ar + 32  + f0 + 2*p) = make_float2(mn[2*p], mn[2*p+1]);
                    *(float2*)(ar + 64  + f0 + 2*p) = make_float2(mx[2*p], mx[2*p+1]);
                    *(float2*)(ar + 96  + f0 + 2*p) = make_float2(sd0, sd1);
                }
            }
            // const h1 rows 0..2, written once with last chunk
            if (c == 3) {
                unsigned p0 = f2bf(h1c[f0+0]) | (f2bf(h1c[f0+1]) << 16);
                unsigned p1 = f2bf(h1c[f0+2]) | (f2bf(h1c[f0+3]) << 16);
                unsigned p2 = f2bf(h1c[f0+4]) | (f2bf(h1c[f0+5]) << 16);
                unsigned p3 = f2bf(h1c[f0+6]) | (f2bf(h1c[f0+7]) << 16);
                if (x1 == 0) {
                    if (ng == 0) {
#pragma unroll
                        for (int r = 0; r < 2; r++) {
                            uint2* d = (uint2*)(sH1 + s * H1_RS + r * H1_NS + f0);
                            d[0] = make_uint2(p0, p1); d[1] = make_uint2(p2, p3);
                        }
                    } else {
                        uint2* d = (uint2*)(sH1 + s * H1_RS + 2 * H1_NS + f0);
                        d[0] = make_uint2(p0, p1); d[1] = make_uint2(p2, p3);
                    }
                }
            }
        } else {
            // ---- conv2: per-wave h2 partial straight from registers
            const float* wvA = (c < 3) ? (w2 + 128) : w2;          // ng=0 class
            const float* wvB = (c < 3) ? (w2 + 128) : (w2 + 256);  // ng=1 class
            float partial = 0.f;
#pragma unroll
            for (int f = 0; f < 8; f++) {
                float me = sm[f] * inv;
                float q  = sq[f] * inv;
                float sd = sqrtf(fmaxf(q - me*me, 0.f) + 1e-5f);
                float wm  = ng ? wvB[f0+f]      : wvA[f0+f];
                float wmn = ng ? wvB[32+f0+f]   : wvA[32+f0+f];
                float wmx = ng ? wvB[64+f0+f]   : wvA[64+f0+f];
                float wsd = ng ? wvB[96+f0+f]   : wvA[96+f0+f];
                partial += me*wm + mn[f]*wmn + mx[f]*wmx + sd*wsd;
            }
            if (x1 == 0) pp[w * 32 + (lane & 31)] = partial;
        }
        __syncthreads();     // agg / partials ready
        // ---- post pass(es)
        if constexpr (CONV == 1) {
            if (c < 3) {
                const float* WE = WEFF + 4096;                 // class 1
                const float* ar = sAGG + ng * AG_SL + s * AG_RS;
                float acc[8];
#pragma unroll
                for (int f = 0; f < 8; f++) acc[f] = bpost[f0 + f];
#pragma unroll
                for (int jp = 0; jp < 64; jp++) {
                    float2 a = *(const float2*)(ar + 2*jp);
                    const float* w0 = WE + (2*jp)*32 + f0;
                    const float* w1 = WE + (2*jp+1)*32 + f0;
#pragma unroll
                    for (int f = 0; f < 8; f++) acc[f] += a.x*w0[f] + a.y*w1[f];
                }
                if (x1 == 0) {
                    uint2* d = (uint2*)(sH1 + s * H1_RS + nd * H1_NS + f0);
                    d[0] = make_uint2(f2bf(fmaxf(acc[0],0.f)) | (f2bf(fmaxf(acc[1],0.f))<<16),
                                      f2bf(fmaxf(acc[2],0.f)) | (f2bf(fmaxf(acc[3],0.f))<<16));
                    d[1] = make_uint2(f2bf(fmaxf(acc[4],0.f)) | (f2bf(fmaxf(acc[5],0.f))<<16),
                                      f2bf(fmaxf(acc[6],0.f)) | (f2bf(fmaxf(acc[7],0.f))<<16));
                }
            } else {
#pragma unroll
                for (int pass = 0; pass < 2; pass++) {
                    const int  node = pass ? 10 : 4;
                    const float* WE = WEFF + (pass ? 8192 : 0); // class2 / class0
                    const float* ar = sAGG + pass * AG_SL + s * AG_RS;
                    float acc[8];
#pragma unroll
                    for (int f = 0; f < 8; f++) acc[f] = bpost[f0 + f];
#pragma unroll
                    for (int jp = 0; jp < 64; jp++) {
                        float2 a = *(const float2*)(ar + 2*jp);
                        const float* w0 = WE + (2*jp)*32 + f0;
                        const float* w1 = WE + (2*jp+1)*32 + f0;
#pragma unroll
                        for (int f = 0; f < 8; f++) acc[f] += a.x*w0[f] + a.y*w1[f];
                    }
                    if (lane < 16) {
                        uint2* d = (uint2*)(sH1 + s * H1_RS + node * H1_NS + f0);
                        d[0] = make_uint2(f2bf(fmaxf(acc[0],0.f)) | (f2bf(fmaxf(acc[1],0.f))<<16),
                                          f2bf(fmaxf(acc[2],0.f)) | (f2bf(fmaxf(acc[3],0.f))<<16));
                        d[1] = make_uint2(f2bf(fmaxf(acc[4],0.f)) | (f2bf(fmaxf(acc[5],0.f))<<16),
                                          f2bf(fmaxf(acc[6],0.f)) | (f2bf(fmaxf(acc[7],0.f))<<16));
                    }
                }
            }
        } else {
            // single wave reduces the 4 partials; exactly ONE atomicAdd per node
            if (w == 0 && lane < 32) {
                float h2 = b2[0];
#pragma unroll
                for (int ww = 0; ww < 4; ww++) h2 += pp[ww * 32 + lane];   // 4 waves, not 8!
                float p = 1.f / (1.f + __expf(-h2));
                p += __shfl_xor(p, 1); p += __shfl_xor(p, 2);
                p += __shfl_xor(p, 4); p += __shfl_xor(p, 8);
                if ((lane & 15) == 0) {
                    const int node = (c < 3) ? (lane ? NDB[c] : NDA[c]) : (lane ? 10 : 4);
                    atomicAdd(gacc + (node - 3), p);
                }
            }
        }
        __syncthreads();     // agg/pp slot reuse
    }
}

extern "C" __global__ void __launch_bounds__(TPB, 3)
pna_main(const float* __restrict__ x_input, const float* __restrict__ edge_attr,
         const float* __restrict__ W_emb,  const float* __restrict__ b_emb,
         const float* __restrict__ W_pre1, const float* __restrict__ b_pre1,
         const float* __restrict__ b_post1,
         const float* __restrict__ W_pre2, const float* __restrict__ b_pre2,
         const float* __restrict__ b_post2,
         float* __restrict__ ws)
{
    __shared__ float          sH[SPB * H_RS];
    __shared__ unsigned short sH1[SPB * H1_RS];
    __shared__ float          sAGG[2 * AG_SL];

    const int tid  = threadIdx.x;
    const int w    = __builtin_amdgcn_readfirstlane(tid >> 6);   // 0..3
    const int lane = tid & 63;
    const int s    = lane & 15;
    const int ng   = (lane >> 4) & 1;
    const int x1   = lane >> 5;
    const int f0   = w * 8;
    const int s0g  = blockIdx.x * SPB;

    // ---- embed (once): H[n] = relu(X[n] @ W_emb[n] + b_emb[n])
    {
        const float* Xp = x_input + (size_t)(s0g + s) * 44;
#pragma unroll
        for (int n = 0; n < 11; n++) {
            float4 xv = *(const float4*)(Xp + n * 4);
            const float* wb = W_emb + n * 128 + f0;
            float acc[8];
#pragma unroll
            for (int f = 0; f < 8; f++)
                acc[f] = b_emb[n*32 + f0 + f]
                       + xv.x*wb[f] + xv.y*wb[32+f] + xv.z*wb[64+f] + xv.w*wb[96+f];
            if (lane < 16) {
                float* hr = sH + s * H_RS + n * H_NS + f0;
#pragma unroll
                for (int p = 0; p < 4; p++)
                    *(float2*)(hr + 2*p) = make_float2(fmaxf(acc[2*p],0.f), fmaxf(acc[2*p+1],0.f));
            }
        }
    }
    __syncthreads();

    for (int i = 0; i < 3; i++) {
        float* gacc = ws + WS_GACC + i * 8;
        run_conv<1>(s, ng, x1, lane, f0, s0g, sH, sH1, sAGG,
                    W_pre1 + i*2176, b_pre1 + i*32,
                    ws + WS_WEFF + i*12288, b_post1 + i*32,
                    nullptr, nullptr, ws + WS_H1C + i*32,
                    edge_attr, gacc, w);
        run_conv<2>(s, ng, x1, lane, f0, s0g, sH, sH1, sAGG,
                    W_pre2 + i*2176, b_pre2 + i*32,
                    nullptr, nullptr,
                    ws + WS_W2E + i*384, b_post2 + i, nullptr,
                    edge_attr, gacc, w);
    }
}

// ---------------- prep kernels ----------------
extern "C" __global__ void pna_prep1(const float* __restrict__ W_post1,
                                     const float* __restrict__ W_post2,
                                     float* __restrict__ ws)
{
    int t = blockIdx.x * 256 + threadIdx.x;
    const float AVGL = 0.9976091242438673f;
    if (t < 36864) {
        int i = t / 12288, r = t % 12288, c = r / 4096, q = r % 4096;
        float logd = (c == 0) ? 0.6931471805599453f : (c == 1) ? 1.0986122886681098f : 1.6094379124341003f;
        float amp = logd / AVGL, att = AVGL / logd;
        const float* W = W_post1 + i * 12288;
        ws[t] = W[q] + amp * W[4096 + q] + att * W[8192 + q];
    } else if (t < 38016) {
        int t2 = t - 36864;
        int i = t2 / 384, r = t2 % 384, c = r / 128, j = r % 128;
        float logd = (c == 0) ? 0.6931471805599453f : (c == 1) ? 1.0986122886681098f : 1.6094379124341003f;
        float amp = logd / AVGL, att = AVGL / logd;
        const float* W = W_post2 + i * 384;
        ws[t] = W[j] + amp * W[128 + j] + att * W[256 + j];
    }
}

extern "C" __global__ void pna_prep2(const float* __restrict__ b_post1,
                                     const float* __restrict__ b_post2,
                                     float* __restrict__ ws)
{
    int t = threadIdx.x;
    if (t < 96) {
        int i = t >> 5, f = t & 31;
        const float* WE = ws + WS_WEFF + i * 12288;   // class 0
        float ssum = 0.f;
        for (int j = 96; j < 128; j++) ssum += WE[j*32 + f];
        ws[WS_H1C + i*32 + f] = fmaxf(b_post1[i*32 + f] + SQRT1EM5 * ssum, 0.f);
    } else if (t < 99) {
        int i = t - 96;
        const float* wv = ws + WS_W2E + i * 384;      // class 0
        float ssum = 0.f;
        for (int j = 96; j < 128; j++) ssum += wv[j];
        float h2 = b_post2[i] + SQRT1EM5 * ssum;
        ws[WS_PC + i] = 1.f / (1.f + __expf(-h2));
    } else if (t < 123) {
        ws[WS_GACC + (t - 99)] = 0.f;
    }
}

extern "C" __global__ void pna_final(const float* __restrict__ W_fc,
                                     const float* __restrict__ b_fc,
                                     const float* __restrict__ ws,
                                     float* __restrict__ out)
{
    int i = threadIdx.x;
    if (i < 3) {
        const float* g = ws + WS_GACC + i * 8;
        float acc = 0.f;
        for (int k = 0; k < 8; k++) acc += g[k] * W_fc[i*11 + 3 + k];
        acc *= (1.f / 16384.f);
        acc += ws[WS_PC + i] * (W_fc[i*11] + W_fc[i*11+1] + W_fc[i*11+2]);
        out[i] = acc + b_fc[i];
    }
}

extern "C" void kernel_launch(void* const* d_in, const int* in_sizes, int n_in,
                              void* d_out, int out_size, void* d_ws, size_t ws_size,
                              hipStream_t stream)
{
    (void)in_sizes; (void)n_in; (void)out_size; (void)ws_size;
    const float* x_input   = (const float*)d_in[0];
    const float* edge_attr = (const float*)d_in[1];
    const float* W_emb     = (const float*)d_in[2];
    const float* b_emb     = (const float*)d_in[3];
    const float* W_pre1    = (const float*)d_in[4];
    const float* b_pre1    = (const float*)d_in[5];
    const float* W_post1   = (const float*)d_in[6];
    const float* b_post1   = (const float*)d_in[7];
    const float* W_pre2    = (const float*)d_in[8];
    const float* b_pre2    = (const float*)d_in[9];
    const float* W_post2   = (const float*)d_in[10];
    const float* b_post2   = (const float*)d_in[11];
    const float* W_fc      = (const float*)d_in[12];
    const float* b_fc      = (const float*)d_in[13];
    float* ws  = (float*)d_ws;
    float* out = (float*)d_out;

    hipLaunchKernelGGL(pna_prep1, dim3(149), dim3(256), 0, stream, W_post1, W_post2, ws);
    hipLaunchKernelGGL(pna_prep2, dim3(1), dim3(128), 0, stream, b_post1, b_post2, ws);
    hipLaunchKernelGGL(pna_main, dim3(NBLK), dim3(TPB), 0, stream,
                       x_input, edge_attr, W_emb, b_emb,
                       W_pre1, b_pre1, b_post1,
                       W_pre2, b_pre2, b_post2, ws);
    hipLaunchKernelGGL(pna_final, dim3(1), dim3(64), 0, stream, W_fc, b_fc, ws, out);
}

// Round 6
// 2794.098 us; speedup vs baseline: 3.0236x; 3.0236x over previous
//
#include <hip/hip_runtime.h>
#include <math.h>

#define TPB  256            // 4 waves of 64
#define SPB  16
#define NBLK 1024           // 16384 / 16  (grid.y = 3 interventions)

// LDS strides (elements)
#define H_RS  378           // float row stride per sample
#define H_NS  34            // float node stride
#define H1_RS 404           // ushort row stride
#define H1_NS 36            // ushort node stride (72 B, b64-aligned)
#define AG_RS 130           // float stride per sample
#define AG_SL (16*AG_RS)    // slot stride (2 node slots)

// ws offsets (floats)
#define WS_WEFF 0           // [3 int][3 class][128 j][32 f] = 36864
#define WS_W2E  36864       // [3 int][3 class][128 j] = 1152
#define WS_H1C  38016       // [3 int][32 f] const h1 rows
#define WS_PC   38112       // [3] const sigmoid p for nodes 0..2
#define WS_GACC 38120       // [3 int][8 node] sums of p

#define SQRT1EM5 0.0031622776601683794f

__device__ __forceinline__ unsigned f2bf(float x) {
    unsigned u = __float_as_uint(x);
    return (u + 0x7fffu + ((u >> 16) & 1u)) >> 16;
}

// One chunk of one PNA conv. lane = s(4b) + ng*16 + x1*32; wave w -> f0 = 8w.
// Chunks (dst-node pairs): C0={3,5} C1={6,7} C2={8,9} (deg2)  C3={4,10} (deg1,deg4).
// ALL graph constants are compile-time scalars — no local arrays, no runtime loop bounds.
template<int CONV, int C>
__device__ __forceinline__ void conv_chunk(
    int s, int ng, int x1, int lane, int w, int f0,
    float* sH, unsigned short* sH1, float* sAGG,
    const float4* eap,
    const float* __restrict__ Wpre, const float* __restrict__ bpre,
    const float* __restrict__ WEFF, const float* __restrict__ bpost,   // conv1
    const float* __restrict__ w2,   const float* __restrict__ b2,      // conv2
    const float* __restrict__ h1c,  float* __restrict__ gacc)
{
    constexpr int ND_A = (C==0)?3:(C==1)?6:(C==2)?8:4;
    constexpr int ND_B = (C==0)?5:(C==1)?7:(C==2)?9:10;
    constexpr int NIT  = (C==3)?2:1;
    const int nd = ng ? ND_B : ND_A;

    // ---- dst-part + bias -> m_base
    float mb[8];
#pragma unroll
    for (int f = 0; f < 8; f++) mb[f] = bpre[f0 + f];
    if constexpr (CONV == 1) {
        const float2* hp = (const float2*)(sH + s * H_RS + nd * H_NS);
#pragma unroll
        for (int kp = 0; kp < 16; kp++) {
            float2 a = hp[kp];
            const float* w0 = Wpre + (2*kp)*32 + f0;
            const float* w1 = Wpre + (2*kp+1)*32 + f0;
#pragma unroll
            for (int f = 0; f < 8; f++) mb[f] += a.x*w0[f] + a.y*w1[f];
        }
    } else {
        const uint2* hp = (const uint2*)(sH1 + s * H1_RS + nd * H1_NS);
#pragma unroll
        for (int kq = 0; kq < 8; kq++) {
            uint2 a = hp[kq];
            float a0 = __uint_as_float(a.x << 16);
            float a1 = __uint_as_float(a.x & 0xffff0000u);
            float a2 = __uint_as_float(a.y << 16);
            float a3 = __uint_as_float(a.y & 0xffff0000u);
            const float* wr = Wpre + (4*kq)*32 + f0;
#pragma unroll
            for (int f = 0; f < 8; f++)
                mb[f] += a0*wr[f] + a1*wr[32+f] + a2*wr[64+f] + a3*wr[96+f];
        }
    }

    // ---- edges + streaming stats
    float sm[8], sq[8], mn[8], mx[8];
#pragma unroll
    for (int f = 0; f < 8; f++) { sm[f] = 0.f; sq[f] = 0.f; mn[f] = 1e30f; mx[f] = -1e30f; }
#pragma unroll
    for (int it = 0; it < NIT; it++) {
        int e, sn;
        if constexpr (C==0)      { e = ng ? (x1?4:3)   : (x1?2:0);   sn = ng ? (x1?2:1) : (x1?1:0); }
        else if constexpr (C==1) { e = ng ? (x1?8:7)   : (x1?6:5);   sn = ng ? (x1?5:4) : (x1?3:0); }
        else if constexpr (C==2) { e = ng ? (x1?12:11) : (x1?10:9);  sn = ng ? (x1?8:2) : (x1?7:6); }
        else {
            if (it == 0) { e = ng ? (x1?15:13) : (x1?-1:1); sn = ng ? (x1?9:3) : 0; }
            else         { e = ng ? (x1?16:14) : -1;        sn = ng ? (x1?1:6) : 0; }
        }
        const bool val = (e >= 0);
        const int  e0  = val ? e : 0;
        float t[8];
        float4 ev = eap[e0];
        {
            const float* wa = Wpre + 64*32 + f0;
#pragma unroll
            for (int f = 0; f < 8; f++)
                t[f] = ev.x*wa[f] + ev.y*wa[32+f] + ev.z*wa[64+f] + ev.w*wa[96+f];
        }
        if constexpr (CONV == 1) {
            const float2* hp = (const float2*)(sH + s * H_RS + sn * H_NS);
#pragma unroll
            for (int kp = 0; kp < 16; kp++) {
                float2 a = hp[kp];
                const float* w0 = Wpre + (32 + 2*kp)*32 + f0;
                const float* w1 = Wpre + (32 + 2*kp+1)*32 + f0;
#pragma unroll
                for (int f = 0; f < 8; f++) t[f] += a.x*w0[f] + a.y*w1[f];
            }
        } else {
            const uint2* hp = (const uint2*)(sH1 + s * H1_RS + sn * H1_NS);
#pragma unroll
            for (int kq = 0; kq < 8; kq++) {
                uint2 a = hp[kq];
                float a0 = __uint_as_float(a.x << 16);
                float a1 = __uint_as_float(a.x & 0xffff0000u);
                float a2 = __uint_as_float(a.y << 16);
                float a3 = __uint_as_float(a.y & 0xffff0000u);
                const float* wr = Wpre + (32 + 4*kq)*32 + f0;
#pragma unroll
                for (int f = 0; f < 8; f++)
                    t[f] += a0*wr[f] + a1*wr[32+f] + a2*wr[64+f] + a3*wr[96+f];
            }
        }
#pragma unroll
        for (int f = 0; f < 8; f++) {
            float m = fmaxf(mb[f] + t[f], 0.f);
            sm[f] += val ? m : 0.f;
            sq[f] += val ? m*m : 0.f;
            mn[f] = fminf(mn[f], val ? m :  1e30f);
            mx[f] = fmaxf(mx[f], val ? m : -1e30f);
        }
    }
    // ---- merge x1 halves
#pragma unroll
    for (int f = 0; f < 8; f++) {
        sm[f] += __shfl_xor(sm[f], 32);
        sq[f] += __shfl_xor(sq[f], 32);
        mn[f] = fminf(mn[f], __shfl_xor(mn[f], 32));
        mx[f] = fmaxf(mx[f], __shfl_xor(mx[f], 32));
    }
    const float inv = (C==3) ? (ng ? 0.25f : 1.0f) : 0.5f;

    if constexpr (CONV == 1) {
        // ---- finalize + agg write (x1 == 0 lanes)
        if (x1 == 0) {
            float* ar = sAGG + ng * AG_SL + s * AG_RS;
#pragma unroll
            for (int p = 0; p < 4; p++) {
                float me0 = sm[2*p] * inv,  me1 = sm[2*p+1] * inv;
                float q0  = sq[2*p] * inv,  q1  = sq[2*p+1] * inv;
                float sd0 = sqrtf(fmaxf(q0 - me0*me0, 0.f) + 1e-5f);
                float sd1 = sqrtf(fmaxf(q1 - me1*me1, 0.f) + 1e-5f);
                *(float2*)(ar +       f0 + 2*p) = make_float2(me0, me1);
                *(float2*)(ar + 32  + f0 + 2*p) = make_float2(mn[2*p], mn[2*p+1]);
                *(float2*)(ar + 64  + f0 + 2*p) = make_float2(mx[2*p], mx[2*p+1]);
                *(float2*)(ar + 96  + f0 + 2*p) = make_float2(sd0, sd1);
            }
        }
        // const h1 rows 0..2 (deg-0 nodes), written once with last chunk
        if constexpr (C == 3) {
            unsigned p0 = f2bf(h1c[f0+0]) | (f2bf(h1c[f0+1]) << 16);
            unsigned p1 = f2bf(h1c[f0+2]) | (f2bf(h1c[f0+3]) << 16);
            unsigned p2 = f2bf(h1c[f0+4]) | (f2bf(h1c[f0+5]) << 16);
            unsigned p3 = f2bf(h1c[f0+6]) | (f2bf(h1c[f0+7]) << 16);
            if (x1 == 0) {
                if (ng == 0) {
#pragma unroll
                    for (int r = 0; r < 2; r++) {
                        uint2* d = (uint2*)(sH1 + s * H1_RS + r * H1_NS + f0);
                        d[0] = make_uint2(p0, p1); d[1] = make_uint2(p2, p3);
                    }
                } else {
                    uint2* d = (uint2*)(sH1 + s * H1_RS + 2 * H1_NS + f0);
                    d[0] = make_uint2(p0, p1); d[1] = make_uint2(p2, p3);
                }
            }
        }
    } else {
        // ---- conv2: per-wave h2 partial straight from registers
        const float* wvA = (C < 3) ? (w2 + 128) : w2;          // ng=0 class
        const float* wvB = (C < 3) ? (w2 + 128) : (w2 + 256);  // ng=1 class
        float partial = 0.f;
#pragma unroll
        for (int f = 0; f < 8; f++) {
            float me = sm[f] * inv;
            float q  = sq[f] * inv;
            float sd = sqrtf(fmaxf(q - me*me, 0.f) + 1e-5f);
            float wm  = ng ? wvB[f0+f]      : wvA[f0+f];
            float wmn = ng ? wvB[32+f0+f]   : wvA[32+f0+f];
            float wmx = ng ? wvB[64+f0+f]   : wvA[64+f0+f];
            float wsd = ng ? wvB[96+f0+f]   : wvA[96+f0+f];
            partial += me*wm + mn[f]*wmn + mx[f]*wmx + sd*wsd;
        }
        if (x1 == 0) sAGG[w * 32 + (lane & 31)] = partial;     // pp scratch aliases sAGG
    }
    __syncthreads();     // agg / partials ready

    if constexpr (CONV == 1) {
        if constexpr (C < 3) {
            const float* WE = WEFF + 4096;                 // deg-2 class
            const float* ar = sAGG + ng * AG_SL + s * AG_RS;
            float acc[8];
#pragma unroll
            for (int f = 0; f < 8; f++) acc[f] = bpost[f0 + f];
#pragma unroll
            for (int jp = 0; jp < 64; jp++) {
                float2 a = *(const float2*)(ar + 2*jp);
                const float* w0 = WE + (2*jp)*32 + f0;
                const float* w1 = WE + (2*jp+1)*32 + f0;
#pragma unroll
                for (int f = 0; f < 8; f++) acc[f] += a.x*w0[f] + a.y*w1[f];
            }
            if (x1 == 0) {
                uint2* d = (uint2*)(sH1 + s * H1_RS + nd * H1_NS + f0);
                d[0] = make_uint2(f2bf(fmaxf(acc[0],0.f)) | (f2bf(fmaxf(acc[1],0.f))<<16),
                                  f2bf(fmaxf(acc[2],0.f)) | (f2bf(fmaxf(acc[3],0.f))<<16));
                d[1] = make_uint2(f2bf(fmaxf(acc[4],0.f)) | (f2bf(fmaxf(acc[5],0.f))<<16),
                                  f2bf(fmaxf(acc[6],0.f)) | (f2bf(fmaxf(acc[7],0.f))<<16));
            }
        } else {
#pragma unroll
            for (int pass = 0; pass < 2; pass++) {
                const int  node = pass ? 10 : 4;
                const float* WE = WEFF + (pass ? 8192 : 0); // deg4 / deg1 class
                const float* ar = sAGG + pass * AG_SL + s * AG_RS;
                float acc[8];
#pragma unroll
                for (int f = 0; f < 8; f++) acc[f] = bpost[f0 + f];
#pragma unroll
                for (int jp = 0; jp < 64; jp++) {
                    float2 a = *(const float2*)(ar + 2*jp);
                    const float* w0 = WE + (2*jp)*32 + f0;
                    const float* w1 = WE + (2*jp+1)*32 + f0;
#pragma unroll
                    for (int f = 0; f < 8; f++) acc[f] += a.x*w0[f] + a.y*w1[f];
                }
                if (lane < 16) {
                    uint2* d = (uint2*)(sH1 + s * H1_RS + node * H1_NS + f0);
                    d[0] = make_uint2(f2bf(fmaxf(acc[0],0.f)) | (f2bf(fmaxf(acc[1],0.f))<<16),
                                      f2bf(fmaxf(acc[2],0.f)) | (f2bf(fmaxf(acc[3],0.f))<<16));
                    d[1] = make_uint2(f2bf(fmaxf(acc[4],0.f)) | (f2bf(fmaxf(acc[5],0.f))<<16),
                                      f2bf(fmaxf(acc[6],0.f)) | (f2bf(fmaxf(acc[7],0.f))<<16));
                }
            }
        }
    } else {
        // one wave reduces the 4 partials; exactly ONE atomicAdd per node
        if (w == 0 && lane < 32) {
            float h2 = b2[0];
#pragma unroll
            for (int ww = 0; ww < 4; ww++) h2 += sAGG[ww * 32 + lane];
            float p = 1.f / (1.f + __expf(-h2));
            p += __shfl_xor(p, 1); p += __shfl_xor(p, 2);
            p += __shfl_xor(p, 4); p += __shfl_xor(p, 8);
            if ((lane & 15) == 0) {
                const int node = (C < 3) ? (lane ? ND_B : ND_A) : (lane ? 10 : 4);
                atomicAdd(gacc + (node - 3), p);
            }
        }
    }
    __syncthreads();     // agg/pp slot reuse
}

extern "C" __global__ void __launch_bounds__(TPB, 3)
pna_main(const float* __restrict__ x_input, const float* __restrict__ edge_attr,
         const float* __restrict__ W_emb,  const float* __restrict__ b_emb,
         const float* __restrict__ W_pre1, const float* __restrict__ b_pre1,
         const float* __restrict__ b_post1,
         const float* __restrict__ W_pre2, const float* __restrict__ b_pre2,
         const float* __restrict__ b_post2,
         float* __restrict__ ws)
{
    __shared__ float          sH[SPB * H_RS];
    __shared__ unsigned short sH1[SPB * H1_RS];
    __shared__ float          sAGG[2 * AG_SL];

    const int tid  = threadIdx.x;
    const int w    = __builtin_amdgcn_readfirstlane(tid >> 6);   // 0..3
    const int lane = tid & 63;
    const int s    = lane & 15;
    const int ng   = (lane >> 4) & 1;
    const int x1   = lane >> 5;
    const int f0   = w * 8;
    const int s0g  = blockIdx.x * SPB;
    const int i    = blockIdx.y;                                 // intervention

    // ---- embed: H[n] = relu(X[n] @ W_emb[n] + b_emb[n])
    {
        const float* Xp = x_input + (size_t)(s0g + s) * 44;
#pragma unroll
        for (int n = 0; n < 11; n++) {
            float4 xv = *(const float4*)(Xp + n * 4);
            const float* wb = W_emb + n * 128 + f0;
            float acc[8];
#pragma unroll
            for (int f = 0; f < 8; f++)
                acc[f] = b_emb[n*32 + f0 + f]
                       + xv.x*wb[f] + xv.y*wb[32+f] + xv.z*wb[64+f] + xv.w*wb[96+f];
            if (lane < 16) {
                float* hr = sH + s * H_RS + n * H_NS + f0;
#pragma unroll
                for (int p = 0; p < 4; p++)
                    *(float2*)(hr + 2*p) = make_float2(fmaxf(acc[2*p],0.f), fmaxf(acc[2*p+1],0.f));
            }
        }
    }
    __syncthreads();

    const float4* eap = (const float4*)(edge_attr + (size_t)(s0g + s) * 68);
    const float* Wp1 = W_pre1 + i*2176;
    const float* Wp2 = W_pre2 + i*2176;
    const float* WE  = ws + WS_WEFF + i*12288;
    const float* w2e = ws + WS_W2E + i*384;
    const float* h1c = ws + WS_H1C + i*32;
    const float* bp1 = b_pre1 + i*32;
    const float* bq1 = b_post1 + i*32;
    const float* bp2 = b_pre2 + i*32;
    const float* bq2 = b_post2 + i;
    float* gacc = ws + WS_GACC + i*8;

    conv_chunk<1,0>(s,ng,x1,lane,w,f0,sH,sH1,sAGG,eap,Wp1,bp1,WE,bq1,nullptr,nullptr,h1c,gacc);
    conv_chunk<1,1>(s,ng,x1,lane,w,f0,sH,sH1,sAGG,eap,Wp1,bp1,WE,bq1,nullptr,nullptr,h1c,gacc);
    conv_chunk<1,2>(s,ng,x1,lane,w,f0,sH,sH1,sAGG,eap,Wp1,bp1,WE,bq1,nullptr,nullptr,h1c,gacc);
    conv_chunk<1,3>(s,ng,x1,lane,w,f0,sH,sH1,sAGG,eap,Wp1,bp1,WE,bq1,nullptr,nullptr,h1c,gacc);
    conv_chunk<2,0>(s,ng,x1,lane,w,f0,sH,sH1,sAGG,eap,Wp2,bp2,nullptr,nullptr,w2e,bq2,nullptr,gacc);
    conv_chunk<2,1>(s,ng,x1,lane,w,f0,sH,sH1,sAGG,eap,Wp2,bp2,nullptr,nullptr,w2e,bq2,nullptr,gacc);
    conv_chunk<2,2>(s,ng,x1,lane,w,f0,sH,sH1,sAGG,eap,Wp2,bp2,nullptr,nullptr,w2e,bq2,nullptr,gacc);
    conv_chunk<2,3>(s,ng,x1,lane,w,f0,sH,sH1,sAGG,eap,Wp2,bp2,nullptr,nullptr,w2e,bq2,nullptr,gacc);
}

// ---------------- prep kernels ----------------
extern "C" __global__ void pna_prep1(const float* __restrict__ W_post1,
                                     const float* __restrict__ W_post2,
                                     float* __restrict__ ws)
{
    int t = blockIdx.x * 256 + threadIdx.x;
    const float AVGL = 0.9976091242438673f;
    if (t < 36864) {
        int i = t / 12288, r = t % 12288, c = r / 4096, q = r % 4096;
        float logd = (c == 0) ? 0.6931471805599453f : (c == 1) ? 1.0986122886681098f : 1.6094379124341003f;
        float amp = logd / AVGL, att = AVGL / logd;
        const float* W = W_post1 + i * 12288;
        ws[t] = W[q] + amp * W[4096 + q] + att * W[8192 + q];
    } else if (t < 38016) {
        int t2 = t - 36864;
        int i = t2 / 384, r = t2 % 384, c = r / 128, j = r % 128;
        float logd = (c == 0) ? 0.6931471805599453f : (c == 1) ? 1.0986122886681098f : 1.6094379124341003f;
        float amp = logd / AVGL, att = AVGL / logd;
        const float* W = W_post2 + i * 384;
        ws[t] = W[j] + amp * W[128 + j] + att * W[256 + j];
    }
}

extern "C" __global__ void pna_prep2(const float* __restrict__ b_post1,
                                     const float* __restrict__ b_post2,
                                     float* __restrict__ ws)
{
    int t = threadIdx.x;
    if (t < 96) {
        int i = t >> 5, f = t & 31;
        const float* WE = ws + WS_WEFF + i * 12288;   // deg-1 class (cnt_c=1 for deg-0 nodes)
        float ssum = 0.f;
        for (int j = 96; j < 128; j++) ssum += WE[j*32 + f];
        ws[WS_H1C + i*32 + f] = fmaxf(b_post1[i*32 + f] + SQRT1EM5 * ssum, 0.f);
    } else if (t < 99) {
        int i = t - 96;
        const float* wv = ws + WS_W2E + i * 384;      // deg-1 class
        float ssum = 0.f;
        for (int j = 96; j < 128; j++) ssum += wv[j];
        float h2 = b_post2[i] + SQRT1EM5 * ssum;
        ws[WS_PC + i] = 1.f / (1.f + __expf(-h2));
    } else if (t < 123) {
        ws[WS_GACC + (t - 99)] = 0.f;
    }
}

extern "C" __global__ void pna_final(const float* __restrict__ W_fc,
                                     const float* __restrict__ b_fc,
                                     const float* __restrict__ ws,
                                     float* __restrict__ out)
{
    int i = threadIdx.x;
    if (i < 3) {
        const float* g = ws + WS_GACC + i * 8;
        float acc = 0.f;
        for (int k = 0; k < 8; k++) acc += g[k] * W_fc[i*11 + 3 + k];
        acc *= (1.f / 16384.f);
        acc += ws[WS_PC + i] * (W_fc[i*11] + W_fc[i*11+1] + W_fc[i*11+2]);
        out[i] = acc + b_fc[i];
    }
}

extern "C" void kernel_launch(void* const* d_in, const int* in_sizes, int n_in,
                              void* d_out, int out_size, void* d_ws, size_t ws_size,
                              hipStream_t stream)
{
    (void)in_sizes; (void)n_in; (void)out_size; (void)ws_size;
    const float* x_input   = (const float*)d_in[0];
    const float* edge_attr = (const float*)d_in[1];
    const float* W_emb     = (const float*)d_in[2];
    const float* b_emb     = (const float*)d_in[3];
    const float* W_pre1    = (const float*)d_in[4];
    const float* b_pre1    = (const float*)d_in[5];
    const float* W_post1   = (const float*)d_in[6];
    const float* b_post1   = (const float*)d_in[7];
    const float* W_pre2    = (const float*)d_in[8];
    const float* b_pre2    = (const float*)d_in[9];
    const float* W_post2   = (const float*)d_in[10];
    const float* b_post2   = (const float*)d_in[11];
    const float* W_fc      = (const float*)d_in[12];
    const float* b_fc      = (const float*)d_in[13];
    float* ws  = (float*)d_ws;
    float* out = (float*)d_out;

    hipLaunchKernelGGL(pna_prep1, dim3(149), dim3(256), 0, stream, W_post1, W_post2, ws);
    hipLaunchKernelGGL(pna_prep2, dim3(1), dim3(128), 0, stream, b_post1, b_post2, ws);
    hipLaunchKernelGGL(pna_main, dim3(NBLK, 3), dim3(TPB), 0, stream,
                       x_input, edge_attr, W_emb, b_emb,
                       W_pre1, b_pre1, b_post1,
                       W_pre2, b_pre2, b_post2, ws);
    hipLaunchKernelGGL(pna_final, dim3(1), dim3(64), 0, stream, W_fc, b_fc, ws, out);
}

// Round 7
// 2755.638 us; speedup vs baseline: 3.0658x; 1.0140x over previous
//
#include <hip/hip_runtime.h>
#include <math.h>

#define TPB  256            // 4 waves of 64
#define SPB  16
#define NBLK 1024           // 16384 / 16  (grid.y = 3 interventions)

// LDS strides (elements)
#define H_RS  378           // float row stride per sample
#define H_NS  34            // float node stride
#define H1_RS 404           // ushort row stride
#define H1_NS 36            // ushort node stride (72 B, b64-aligned)
#define AG_RS 130           // float stride per sample
#define AG_SL (16*AG_RS)    // slot stride (2 node slots)

// ws offsets (floats)
#define WS_WEFF 0           // [3 int][3 class][128 j][32 f] = 36864
#define WS_W2E  36864       // [3 int][3 class][128 j] = 1152
#define WS_H1C  38016       // [3 int][32 f] const h1 rows
#define WS_PC   38112       // [3] const sigmoid p for nodes 0..2
#define WS_GACC 38120       // [3 int][8 node] sums of p

#define SQRT1EM5 0.0031622776601683794f

__device__ __forceinline__ unsigned f2bf(float x) {
    unsigned u = __float_as_uint(x);
    return (u + 0x7fffu + ((u >> 16) & 1u)) >> 16;
}

// One chunk of one PNA conv. lane = s(4b) + ng*16 + x1*32; wave w -> f0 = 8w.
// Chunks (dst-node pairs): C0={3,5} C1={6,7} C2={8,9} (deg2)  C3={4,10} (deg1,deg4).
// ALL graph constants are compile-time scalars; ALL weight pointers are distinct
// __restrict__ objects so uniform loads scalarize to s_load (the R6 regression was
// WEFF aliasing the atomically-written ws pointer -> per-lane global_load bloat).
template<int CONV, int C>
__device__ __forceinline__ void conv_chunk(
    int s, int ng, int x1, int lane, int w, int f0,
    float* sH, unsigned short* sH1, float* sAGG,
    const float4* eap,
    const float* __restrict__ Wpre, const float* __restrict__ bpre,
    const float* __restrict__ WEFF, const float* __restrict__ bpost,   // conv1
    const float* __restrict__ w2,   const float* __restrict__ b2,      // conv2
    const float* __restrict__ h1c,  float* __restrict__ gacc)
{
    constexpr int ND_A = (C==0)?3:(C==1)?6:(C==2)?8:4;
    constexpr int ND_B = (C==0)?5:(C==1)?7:(C==2)?9:10;
    constexpr int NIT  = (C==3)?2:1;
    const int nd = ng ? ND_B : ND_A;

    // ---- dst-part + bias -> m_base
    float mb[8];
#pragma unroll
    for (int f = 0; f < 8; f++) mb[f] = bpre[f0 + f];
    if constexpr (CONV == 1) {
        const float2* hp = (const float2*)(sH + s * H_RS + nd * H_NS);
#pragma unroll
        for (int kp = 0; kp < 16; kp++) {
            float2 a = hp[kp];
            const float* w0 = Wpre + (2*kp)*32 + f0;
            const float* w1 = Wpre + (2*kp+1)*32 + f0;
#pragma unroll
            for (int f = 0; f < 8; f++) mb[f] += a.x*w0[f] + a.y*w1[f];
        }
    } else {
        const uint2* hp = (const uint2*)(sH1 + s * H1_RS + nd * H1_NS);
#pragma unroll
        for (int kq = 0; kq < 8; kq++) {
            uint2 a = hp[kq];
            float a0 = __uint_as_float(a.x << 16);
            float a1 = __uint_as_float(a.x & 0xffff0000u);
            float a2 = __uint_as_float(a.y << 16);
            float a3 = __uint_as_float(a.y & 0xffff0000u);
            const float* wr = Wpre + (4*kq)*32 + f0;
#pragma unroll
            for (int f = 0; f < 8; f++)
                mb[f] += a0*wr[f] + a1*wr[32+f] + a2*wr[64+f] + a3*wr[96+f];
        }
    }

    // ---- edges + streaming stats
    float sm[8], sq[8], mn[8], mx[8];
#pragma unroll
    for (int f = 0; f < 8; f++) { sm[f] = 0.f; sq[f] = 0.f; mn[f] = 1e30f; mx[f] = -1e30f; }
#pragma unroll
    for (int it = 0; it < NIT; it++) {
        int e, sn;
        if constexpr (C==0)      { e = ng ? (x1?4:3)   : (x1?2:0);   sn = ng ? (x1?2:1) : (x1?1:0); }
        else if constexpr (C==1) { e = ng ? (x1?8:7)   : (x1?6:5);   sn = ng ? (x1?5:4) : (x1?3:0); }
        else if constexpr (C==2) { e = ng ? (x1?12:11) : (x1?10:9);  sn = ng ? (x1?8:2) : (x1?7:6); }
        else {
            if (it == 0) { e = ng ? (x1?15:13) : (x1?-1:1); sn = ng ? (x1?9:3) : 0; }
            else         { e = ng ? (x1?16:14) : -1;        sn = ng ? (x1?1:6) : 0; }
        }
        const bool val = (e >= 0);
        const int  e0  = val ? e : 0;
        float t[8];
        float4 ev = eap[e0];
        {
            const float* wa = Wpre + 64*32 + f0;
#pragma unroll
            for (int f = 0; f < 8; f++)
                t[f] = ev.x*wa[f] + ev.y*wa[32+f] + ev.z*wa[64+f] + ev.w*wa[96+f];
        }
        if constexpr (CONV == 1) {
            const float2* hp = (const float2*)(sH + s * H_RS + sn * H_NS);
#pragma unroll
            for (int kp = 0; kp < 16; kp++) {
                float2 a = hp[kp];
                const float* w0 = Wpre + (32 + 2*kp)*32 + f0;
                const float* w1 = Wpre + (32 + 2*kp+1)*32 + f0;
#pragma unroll
                for (int f = 0; f < 8; f++) t[f] += a.x*w0[f] + a.y*w1[f];
            }
        } else {
            const uint2* hp = (const uint2*)(sH1 + s * H1_RS + sn * H1_NS);
#pragma unroll
            for (int kq = 0; kq < 8; kq++) {
                uint2 a = hp[kq];
                float a0 = __uint_as_float(a.x << 16);
                float a1 = __uint_as_float(a.x & 0xffff0000u);
                float a2 = __uint_as_float(a.y << 16);
                float a3 = __uint_as_float(a.y & 0xffff0000u);
                const float* wr = Wpre + (32 + 4*kq)*32 + f0;
#pragma unroll
                for (int f = 0; f < 8; f++)
                    t[f] += a0*wr[f] + a1*wr[32+f] + a2*wr[64+f] + a3*wr[96+f];
            }
        }
#pragma unroll
        for (int f = 0; f < 8; f++) {
            float m = fmaxf(mb[f] + t[f], 0.f);
            sm[f] += val ? m : 0.f;
            sq[f] += val ? m*m : 0.f;
            mn[f] = fminf(mn[f], val ? m :  1e30f);
            mx[f] = fmaxf(mx[f], val ? m : -1e30f);
        }
    }
    // ---- merge x1 halves
#pragma unroll
    for (int f = 0; f < 8; f++) {
        sm[f] += __shfl_xor(sm[f], 32);
        sq[f] += __shfl_xor(sq[f], 32);
        mn[f] = fminf(mn[f], __shfl_xor(mn[f], 32));
        mx[f] = fmaxf(mx[f], __shfl_xor(mx[f], 32));
    }
    const float inv = (C==3) ? (ng ? 0.25f : 1.0f) : 0.5f;

    if constexpr (CONV == 1) {
        // ---- finalize + agg write (x1 == 0 lanes)
        if (x1 == 0) {
            float* ar = sAGG + ng * AG_SL + s * AG_RS;
#pragma unroll
            for (int p = 0; p < 4; p++) {
                float me0 = sm[2*p] * inv,  me1 = sm[2*p+1] * inv;
                float q0  = sq[2*p] * inv,  q1  = sq[2*p+1] * inv;
                float sd0 = sqrtf(fmaxf(q0 - me0*me0, 0.f) + 1e-5f);
                float sd1 = sqrtf(fmaxf(q1 - me1*me1, 0.f) + 1e-5f);
                *(float2*)(ar +       f0 + 2*p) = make_float2(me0, me1);
                *(float2*)(ar + 32  + f0 + 2*p) = make_float2(mn[2*p], mn[2*p+1]);
                *(float2*)(ar + 64  + f0 + 2*p) = make_float2(mx[2*p], mx[2*p+1]);
                *(float2*)(ar + 96  + f0 + 2*p) = make_float2(sd0, sd1);
            }
        }
        // const h1 rows 0..2 (deg-0 nodes), written once with last chunk
        if constexpr (C == 3) {
            unsigned p0 = f2bf(h1c[f0+0]) | (f2bf(h1c[f0+1]) << 16);
            unsigned p1 = f2bf(h1c[f0+2]) | (f2bf(h1c[f0+3]) << 16);
            unsigned p2 = f2bf(h1c[f0+4]) | (f2bf(h1c[f0+5]) << 16);
            unsigned p3 = f2bf(h1c[f0+6]) | (f2bf(h1c[f0+7]) << 16);
            if (x1 == 0) {
                if (ng == 0) {
#pragma unroll
                    for (int r = 0; r < 2; r++) {
                        uint2* d = (uint2*)(sH1 + s * H1_RS + r * H1_NS + f0);
                        d[0] = make_uint2(p0, p1); d[1] = make_uint2(p2, p3);
                    }
                } else {
                    uint2* d = (uint2*)(sH1 + s * H1_RS + 2 * H1_NS + f0);
                    d[0] = make_uint2(p0, p1); d[1] = make_uint2(p2, p3);
                }
            }
        }
    } else {
        // ---- conv2: per-wave h2 partial straight from registers
        const float* wvA = (C < 3) ? (w2 + 128) : w2;          // ng=0 class
        const float* wvB = (C < 3) ? (w2 + 128) : (w2 + 256);  // ng=1 class
        float partial = 0.f;
#pragma unroll
        for (int f = 0; f < 8; f++) {
            float me = sm[f] * inv;
            float q  = sq[f] * inv;
            float sd = sqrtf(fmaxf(q - me*me, 0.f) + 1e-5f);
            float wm  = ng ? wvB[f0+f]      : wvA[f0+f];
            float wmn = ng ? wvB[32+f0+f]   : wvA[32+f0+f];
            float wmx = ng ? wvB[64+f0+f]   : wvA[64+f0+f];
            float wsd = ng ? wvB[96+f0+f]   : wvA[96+f0+f];
            partial += me*wm + mn[f]*wmn + mx[f]*wmx + sd*wsd;
        }
        if (x1 == 0) sAGG[w * 32 + (lane & 31)] = partial;     // pp scratch aliases sAGG
    }
    __syncthreads();     // agg / partials ready

    if constexpr (CONV == 1) {
        if constexpr (C < 3) {
            const float* WE = WEFF + 4096;                 // deg-2 class
            const float* ar = sAGG + ng * AG_SL + s * AG_RS;
            float acc[8];
#pragma unroll
            for (int f = 0; f < 8; f++) acc[f] = bpost[f0 + f];
#pragma unroll
            for (int jp = 0; jp < 64; jp++) {
                float2 a = *(const float2*)(ar + 2*jp);
                const float* w0 = WE + (2*jp)*32 + f0;
                const float* w1 = WE + (2*jp+1)*32 + f0;
#pragma unroll
                for (int f = 0; f < 8; f++) acc[f] += a.x*w0[f] + a.y*w1[f];
            }
            if (x1 == 0) {
                uint2* d = (uint2*)(sH1 + s * H1_RS + nd * H1_NS + f0);
                d[0] = make_uint2(f2bf(fmaxf(acc[0],0.f)) | (f2bf(fmaxf(acc[1],0.f))<<16),
                                  f2bf(fmaxf(acc[2],0.f)) | (f2bf(fmaxf(acc[3],0.f))<<16));
                d[1] = make_uint2(f2bf(fmaxf(acc[4],0.f)) | (f2bf(fmaxf(acc[5],0.f))<<16),
                                  f2bf(fmaxf(acc[6],0.f)) | (f2bf(fmaxf(acc[7],0.f))<<16));
            }
        } else {
#pragma unroll
            for (int pass = 0; pass < 2; pass++) {
                const int  node = pass ? 10 : 4;
                const float* WE = WEFF + (pass ? 8192 : 0); // deg4 / deg1 class
                const float* ar = sAGG + pass * AG_SL + s * AG_RS;
                float acc[8];
#pragma unroll
                for (int f = 0; f < 8; f++) acc[f] = bpost[f0 + f];
#pragma unroll
                for (int jp = 0; jp < 64; jp++) {
                    float2 a = *(const float2*)(ar + 2*jp);
                    const float* w0 = WE + (2*jp)*32 + f0;
                    const float* w1 = WE + (2*jp+1)*32 + f0;
#pragma unroll
                    for (int f = 0; f < 8; f++) acc[f] += a.x*w0[f] + a.y*w1[f];
                }
                if (lane < 16) {
                    uint2* d = (uint2*)(sH1 + s * H1_RS + node * H1_NS + f0);
                    d[0] = make_uint2(f2bf(fmaxf(acc[0],0.f)) | (f2bf(fmaxf(acc[1],0.f))<<16),
                                      f2bf(fmaxf(acc[2],0.f)) | (f2bf(fmaxf(acc[3],0.f))<<16));
                    d[1] = make_uint2(f2bf(fmaxf(acc[4],0.f)) | (f2bf(fmaxf(acc[5],0.f))<<16),
                                      f2bf(fmaxf(acc[6],0.f)) | (f2bf(fmaxf(acc[7],0.f))<<16));
                }
            }
        }
    } else {
        // one wave reduces the 4 partials; exactly ONE atomicAdd per node
        if (w == 0 && lane < 32) {
            float h2 = b2[0];
#pragma unroll
            for (int ww = 0; ww < 4; ww++) h2 += sAGG[ww * 32 + lane];
            float p = 1.f / (1.f + __expf(-h2));
            p += __shfl_xor(p, 1); p += __shfl_xor(p, 2);
            p += __shfl_xor(p, 4); p += __shfl_xor(p, 8);
            if ((lane & 15) == 0) {
                const int node = (C < 3) ? (lane ? ND_B : ND_A) : (lane ? 10 : 4);
                atomicAdd(gacc + (node - 3), p);
            }
        }
    }
    __syncthreads();     // agg/pp slot reuse
}

extern "C" __global__ void __launch_bounds__(TPB, 3)
pna_main(const float* __restrict__ x_input, const float* __restrict__ edge_attr,
         const float* __restrict__ W_emb,  const float* __restrict__ b_emb,
         const float* __restrict__ W_pre1, const float* __restrict__ b_pre1,
         const float* __restrict__ b_post1,
         const float* __restrict__ W_pre2, const float* __restrict__ b_pre2,
         const float* __restrict__ b_post2,
         const float* __restrict__ weff,   const float* __restrict__ w2eff,
         const float* __restrict__ h1call, float* __restrict__ gaccall)
{
    __shared__ float          sH[SPB * H_RS];
    __shared__ unsigned short sH1[SPB * H1_RS];
    __shared__ float          sAGG[2 * AG_SL];

    const int tid  = threadIdx.x;
    const int w    = __builtin_amdgcn_readfirstlane(tid >> 6);   // 0..3
    const int lane = tid & 63;
    const int s    = lane & 15;
    const int ng   = (lane >> 4) & 1;
    const int x1   = lane >> 5;
    const int f0   = w * 8;
    const int s0g  = blockIdx.x * SPB;
    const int i    = blockIdx.y;                                 // intervention

    // ---- embed: H[n] = relu(X[n] @ W_emb[n] + b_emb[n])
    {
        const float* Xp = x_input + (size_t)(s0g + s) * 44;
#pragma unroll
        for (int n = 0; n < 11; n++) {
            float4 xv = *(const float4*)(Xp + n * 4);
            const float* wb = W_emb + n * 128 + f0;
            float acc[8];
#pragma unroll
            for (int f = 0; f < 8; f++)
                acc[f] = b_emb[n*32 + f0 + f]
                       + xv.x*wb[f] + xv.y*wb[32+f] + xv.z*wb[64+f] + xv.w*wb[96+f];
            if (lane < 16) {
                float* hr = sH + s * H_RS + n * H_NS + f0;
#pragma unroll
                for (int p = 0; p < 4; p++)
                    *(float2*)(hr + 2*p) = make_float2(fmaxf(acc[2*p],0.f), fmaxf(acc[2*p+1],0.f));
            }
        }
    }
    __syncthreads();

    const float4* eap = (const float4*)(edge_attr + (size_t)(s0g + s) * 68);
    const float* Wp1 = W_pre1 + i*2176;
    const float* Wp2 = W_pre2 + i*2176;
    const float* WE  = weff   + i*12288;
    const float* w2e = w2eff  + i*384;
    const float* h1c = h1call + i*32;
    const float* bp1 = b_pre1 + i*32;
    const float* bq1 = b_post1 + i*32;
    const float* bp2 = b_pre2 + i*32;
    const float* bq2 = b_post2 + i;
    float* gacc = gaccall + i*8;

    conv_chunk<1,0>(s,ng,x1,lane,w,f0,sH,sH1,sAGG,eap,Wp1,bp1,WE,bq1,nullptr,nullptr,h1c,gacc);
    conv_chunk<1,1>(s,ng,x1,lane,w,f0,sH,sH1,sAGG,eap,Wp1,bp1,WE,bq1,nullptr,nullptr,h1c,gacc);
    conv_chunk<1,2>(s,ng,x1,lane,w,f0,sH,sH1,sAGG,eap,Wp1,bp1,WE,bq1,nullptr,nullptr,h1c,gacc);
    conv_chunk<1,3>(s,ng,x1,lane,w,f0,sH,sH1,sAGG,eap,Wp1,bp1,WE,bq1,nullptr,nullptr,h1c,gacc);
    conv_chunk<2,0>(s,ng,x1,lane,w,f0,sH,sH1,sAGG,eap,Wp2,bp2,nullptr,nullptr,w2e,bq2,nullptr,gacc);
    conv_chunk<2,1>(s,ng,x1,lane,w,f0,sH,sH1,sAGG,eap,Wp2,bp2,nullptr,nullptr,w2e,bq2,nullptr,gacc);
    conv_chunk<2,2>(s,ng,x1,lane,w,f0,sH,sH1,sAGG,eap,Wp2,bp2,nullptr,nullptr,w2e,bq2,nullptr,gacc);
    conv_chunk<2,3>(s,ng,x1,lane,w,f0,sH,sH1,sAGG,eap,Wp2,bp2,nullptr,nullptr,w2e,bq2,nullptr,gacc);
}

// ---------------- prep kernels ----------------
extern "C" __global__ void pna_prep1(const float* __restrict__ W_post1,
                                     const float* __restrict__ W_post2,
                                     float* __restrict__ ws)
{
    int t = blockIdx.x * 256 + threadIdx.x;
    const float AVGL = 0.9976091242438673f;
    if (t < 36864) {
        int i = t / 12288, r = t % 12288, c = r / 4096, q = r % 4096;
        float logd = (c == 0) ? 0.6931471805599453f : (c == 1) ? 1.0986122886681098f : 1.6094379124341003f;
        float amp = logd / AVGL, att = AVGL / logd;
        const float* W = W_post1 + i * 12288;
        ws[t] = W[q] + amp * W[4096 + q] + att * W[8192 + q];
    } else if (t < 38016) {
        int t2 = t - 36864;
        int i = t2 / 384, r = t2 % 384, c = r / 128, j = r % 128;
        float logd = (c == 0) ? 0.6931471805599453f : (c == 1) ? 1.0986122886681098f : 1.6094379124341003f;
        float amp = logd / AVGL, att = AVGL / logd;
        const float* W = W_post2 + i * 384;
        ws[t] = W[j] + amp * W[128 + j] + att * W[256 + j];
    }
}

extern "C" __global__ void pna_prep2(const float* __restrict__ b_post1,
                                     const float* __restrict__ b_post2,
                                     float* __restrict__ ws)
{
    int t = threadIdx.x;
    if (t < 96) {
        int i = t >> 5, f = t & 31;
        const float* WE = ws + WS_WEFF + i * 12288;   // deg-1 class (cnt_c=1 for deg-0 nodes)
        float ssum = 0.f;
        for (int j = 96; j < 128; j++) ssum += WE[j*32 + f];
        ws[WS_H1C + i*32 + f] = fmaxf(b_post1[i*32 + f] + SQRT1EM5 * ssum, 0.f);
    } else if (t < 99) {
        int i = t - 96;
        const float* wv = ws + WS_W2E + i * 384;      // deg-1 class
        float ssum = 0.f;
        for (int j = 96; j < 128; j++) ssum += wv[j];
        float h2 = b_post2[i] + SQRT1EM5 * ssum;
        ws[WS_PC + i] = 1.f / (1.f + __expf(-h2));
    } else if (t < 123) {
        ws[WS_GACC + (t - 99)] = 0.f;
    }
}

extern "C" __global__ void pna_final(const float* __restrict__ W_fc,
                                     const float* __restrict__ b_fc,
                                     const float* __restrict__ ws,
                                     float* __restrict__ out)
{
    int i = threadIdx.x;
    if (i < 3) {
        const float* g = ws + WS_GACC + i * 8;
        float acc = 0.f;
        for (int k = 0; k < 8; k++) acc += g[k] * W_fc[i*11 + 3 + k];
        acc *= (1.f / 16384.f);
        acc += ws[WS_PC + i] * (W_fc[i*11] + W_fc[i*11+1] + W_fc[i*11+2]);
        out[i] = acc + b_fc[i];
    }
}

extern "C" void kernel_launch(void* const* d_in, const int* in_sizes, int n_in,
                              void* d_out, int out_size, void* d_ws, size_t ws_size,
                              hipStream_t stream)
{
    (void)in_sizes; (void)n_in; (void)out_size; (void)ws_size;
    const float* x_input   = (const float*)d_in[0];
    const float* edge_attr = (const float*)d_in[1];
    const float* W_emb     = (const float*)d_in[2];
    const float* b_emb     = (const float*)d_in[3];
    const float* W_pre1    = (const float*)d_in[4];
    const float* b_pre1    = (const float*)d_in[5];
    const float* W_post1   = (const float*)d_in[6];
    const float* b_post1   = (const float*)d_in[7];
    const float* W_pre2    = (const float*)d_in[8];
    const float* b_pre2    = (const float*)d_in[9];
    const float* W_post2   = (const float*)d_in[10];
    const float* b_post2   = (const float*)d_in[11];
    const float* W_fc      = (const float*)d_in[12];
    const float* b_fc      = (const float*)d_in[13];
    float* ws  = (float*)d_ws;
    float* out = (float*)d_out;

    hipLaunchKernelGGL(pna_prep1, dim3(149), dim3(256), 0, stream, W_post1, W_post2, ws);
    hipLaunchKernelGGL(pna_prep2, dim3(1), dim3(128), 0, stream, b_post1, b_post2, ws);
    hipLaunchKernelGGL(pna_main, dim3(NBLK, 3), dim3(TPB), 0, stream,
                       x_input, edge_attr, W_emb, b_emb,
                       W_pre1, b_pre1, b_post1,
                       W_pre2, b_pre2, b_post2,
                       ws + WS_WEFF, ws + WS_W2E, ws + WS_H1C, ws + WS_GACC);
    hipLaunchKernelGGL(pna_final, dim3(1), dim3(64), 0, stream, W_fc, b_fc, ws, out);
}